// Round 3
// baseline (311.933 us; speedup 1.0000x reference)
//
#include <hip/hip_runtime.h>
#include <math.h>

// Problem constants: B=64, MAX_H=64, MAX_W=32, D=512, S=8, HID=64
#define NB    64
#define MAXH  64
#define MAXW  32
#define DCH   512
#define SS    8
#define HID   64

#define QTOTAL ((size_t)NB * MAXH * MAXW * DCH)   // 67,108,864 floats

typedef float f4  __attribute__((ext_vector_type(4)));
typedef short s8v __attribute__((ext_vector_type(8)));   // 8 bf16 (4 VGPRs)

__device__ __forceinline__ float gelu_exact(float x) {
    // jax.nn.gelu(approximate=False): x * 0.5 * (1 + erf(x/sqrt(2)))
    return 0.5f * x * (1.0f + erff(x * 0.70710678118654752440f));
}

__device__ __forceinline__ unsigned short bf16_rne(float x) {
    unsigned int u = __float_as_uint(x);
    unsigned int r = u + 0x7fffu + ((u >> 16) & 1u);
    return (unsigned short)(r >> 16);
}

// ---------------------------------------------------------------------------
// Prep: w2 (64x512 f32) -> bf16 table in MFMA fragment order (64 KB, d_ws).
// Lane l holds elems [k=(l>>4)*8+j][x=l&15], j=0..7 — identical packing for
// the A-fragment (x=M-row) and B-fragment (x=N-col) of 16x16x32 bf16 MFMA.
//   k = 32*kh + (l>>4)*8 + j,  c = 16*ct + (l&15)
// Flat index = (kh*32 + ct)*64 + lane  (== tid below).
// ---------------------------------------------------------------------------
__global__ __launch_bounds__(256) void w2prep_kernel(
    const float* __restrict__ w2, s8v* __restrict__ w2b)
{
    const int tid  = blockIdx.x * 256 + threadIdx.x;   // 0..4095
    const int lane = tid & 63;
    const int ct   = (tid >> 6) & 31;
    const int kh   = tid >> 11;                        // 0..1
    const int q    = lane >> 4;
    const int m    = lane & 15;
    const int c    = ct * 16 + m;
    union { s8v v; unsigned short us[8]; } pk;
    #pragma unroll
    for (int j = 0; j < 8; ++j) {
        const int k = kh * 32 + q * 8 + j;
        pk.us[j] = bf16_rne(w2[k * DCH + c]);
    }
    w2b[tid] = pk.v;
}

// ---------------------------------------------------------------------------
// Main (R3): one block = (b, i) -> ALL 32 j x 512 c. 4 waves, each wave owns
// 128 channels = 8 MFMA tiles; each tile feeds both j-halves (4 MFMAs).
//
// R3 changes vs R2:
//  * ALL output stores are NON-TEMPORAL (output is never re-read; avoids
//    L2 write-back pressure right after the 1 GB poison fill dirtied L2).
//  * removed the W<=16 divergent skip (saved compute below the write
//    roofline; cost registers/divergence) — always compute both halves.
//  * __launch_bounds__(256,2): no spill risk; 3+ blocks/CU is ample for a
//    write-drain-bound kernel.
//
// MFMA operand order (R1, verified): A = w2 fragment, B = h fragment ->
// D layout col = lane&15 = j_local, row = (lane>>4)*4 + r = c_local, so each
// lane stores 4 consecutive channels of one j-row (global_store_dwordx4).
// ---------------------------------------------------------------------------
__global__ __launch_bounds__(256, 2) void hgqg_kernel(
    const float* __restrict__ canonical,  // (8,8,512)
    const float* __restrict__ w1,         // (2,64)
    const float* __restrict__ b1,         // (64,)
    const s8v*   __restrict__ w2b,        // bf16 fragment table (d_ws)
    const float* __restrict__ b2,         // (512,)
    const int*   __restrict__ hlist,      // (64,)
    const int*   __restrict__ wlist,      // (64,)
    float* __restrict__ out)              // queries flat, then mask flat
{
    // bijective swizzle: consecutive blocks cycle through b (mixes H values
    // across co-scheduled blocks), i shifted per b.
    const int raw = blockIdx.x;                  // 0..4095
    const int b   = raw & 63;
    const int i   = ((raw >> 6) + b) & 63;
    const int blk = (b << 6) | i;
    const int t   = threadIdx.x;

    int H = hlist[b]; H = min(max(H, 1), MAXH);
    int W = wlist[b]; W = min(max(W, 1), MAXW);

    if (t < MAXW) {
        __builtin_nontemporal_store((i < H && t < W) ? 1.0f : 0.0f,
                                    out + QTOTAL + (size_t)blk * MAXW + t);
    }

    float* obase = out + (size_t)blk * (MAXW * DCH);
    f4* q4 = (f4*)obase;
    const f4 z = {0.f, 0.f, 0.f, 0.f};

    if (i >= H) {                      // whole (b,i) row masked: zero 64 KB
        #pragma unroll
        for (int r = 0; r < 16; ++r)
            __builtin_nontemporal_store(z, q4 + t + r * 256);
        return;
    }

    // ---- per-row uniforms ----
    const float u    = (H > 1) ? (float)i / (float)(H - 1) : 0.0f;
    const float sy   = fminf(u * 7.0f, 7.0f);
    const int   y0   = (int)sy;
    const int   y1   = min(y0 + 1, SS - 1);
    const float wy   = sy - (float)y0;
    const float winv = (W > 1) ? 1.0f / (float)(W - 1) : 0.0f;

    // ---- stage A: y-lerped canonical rows -> LDS, padded stride 516 ----
    __shared__ __align__(16) float ri[SS * 516];     // 16.5 KB
    {
        const f4* can4 = (const f4*)canonical;
        #pragma unroll
        for (int rr = 0; rr < 4; ++rr) {
            const int idx = t + rr * 256;     // 0..1023
            const int x   = idx >> 7;
            const int c4  = idx & 127;
            const f4 a = can4[(y0 * SS + x) * 128 + c4];
            const f4 d = can4[(y1 * SS + x) * 128 + c4];
            *(f4*)&ri[x * 516 + c4 * 4] = a + wy * (d - a);
        }
    }

    // ---- stage B: hsh[jl][k] = gelu(u*w1[0][k] + v*w1[1][k] + b1[k]) ----
    __shared__ __align__(16) float hsh[32][68];      // 8.7 KB, padded
    {
        const int jl = t >> 3;              // 0..31
        const int k0 = (t & 7) * 8;         // 0..56
        const float v = (float)jl * winv;
        #pragma unroll
        for (int kk = 0; kk < 8; ++kk) {
            const int k = k0 + kk;
            hsh[jl][k] = gelu_exact(u * w1[k] + v * w1[HID + k] + b1[k]);
        }
    }
    __syncthreads();

    // ---- wave decomposition ----
    const int l = t & 63;          // lane
    const int w = t >> 6;          // wave 0..3 -> channels [w*128, w*128+128)
    const int q = l >> 4;          // quad
    const int m = l & 15;          // lane-in-quad

    // h-fragments (MFMA B operand): lane holds h[j = hh*16 + m][k = q*8 + j]
    union { s8v v; unsigned short us[8]; } A0h0, A1h0, A0h1, A1h1;
    {
        const float* hrow0 = &hsh[m][q * 8];
        const float* hrow1 = &hsh[16 + m][q * 8];
        #pragma unroll
        for (int j = 0; j < 8; ++j) {
            A0h0.us[j] = bf16_rne(hrow0[j]);
            A1h0.us[j] = bf16_rne(hrow0[32 + j]);
            A0h1.us[j] = bf16_rne(hrow1[j]);
            A1h1.us[j] = bf16_rne(hrow1[32 + j]);
        }
    }

    // per-lane x-weights for this lane's two j-rows: j0 = m, j1 = 16 + m
    const float v0  = (float)m * winv;
    const float sx0 = fminf(v0 * 7.0f, 7.0f);
    const int   x00 = (int)sx0;
    const int   x01 = min(x00 + 1, SS - 1);
    const float wx0 = sx0 - (float)x00;
    const bool  jok0 = (m < W);

    const float v1  = (float)(16 + m) * winv;
    const float sx1 = fminf(v1 * 7.0f, 7.0f);
    const int   x10 = (int)sx1;
    const int   x11 = min(x10 + 1, SS - 1);
    const float wx1 = sx1 - (float)x10;
    const bool  jok1 = (16 + m < W);

    float* orow0 = obase + (size_t)m * DCH;
    float* orow1 = obase + (size_t)(16 + m) * DCH;

    #pragma unroll
    for (int tt = 0; tt < 8; ++tt) {
        const int ct = w * 8 + tt;           // c-tile 0..31
        const int cb = ct * 16 + q * 4;      // 4 consecutive channels / lane

        const s8v b0  = w2b[ct * 64 + l];            // kh=0
        const s8v b1f = w2b[2048 + ct * 64 + l];     // kh=1
        const f4  bb  = *(const f4*)&b2[cb];

        // half 0: j = m
        {
            const f4 f0 = *(const f4*)&ri[x00 * 516 + cb];
            const f4 f1 = *(const f4*)&ri[x01 * 516 + cb];
            f4 acc = f0 + wx0 * (f1 - f0) + bb;
            acc = __builtin_amdgcn_mfma_f32_16x16x32_bf16(b0,  A0h0.v, acc, 0, 0, 0);
            acc = __builtin_amdgcn_mfma_f32_16x16x32_bf16(b1f, A1h0.v, acc, 0, 0, 0);
            __builtin_nontemporal_store(jok0 ? acc : z, (f4*)(orow0 + cb));
        }
        // half 1: j = 16 + m
        {
            const f4 g0 = *(const f4*)&ri[x10 * 516 + cb];
            const f4 g1 = *(const f4*)&ri[x11 * 516 + cb];
            f4 a2 = g0 + wx1 * (g1 - g0) + bb;
            a2 = __builtin_amdgcn_mfma_f32_16x16x32_bf16(b0,  A0h1.v, a2, 0, 0, 0);
            a2 = __builtin_amdgcn_mfma_f32_16x16x32_bf16(b1f, A1h1.v, a2, 0, 0, 0);
            __builtin_nontemporal_store(jok1 ? a2 : z, (f4*)(orow1 + cb));
        }
    }
}

extern "C" void kernel_launch(void* const* d_in, const int* in_sizes, int n_in,
                              void* d_out, int out_size, void* d_ws, size_t ws_size,
                              hipStream_t stream) {
    const float* canonical = (const float*)d_in[0];
    const float* w1        = (const float*)d_in[1];
    const float* b1        = (const float*)d_in[2];
    const float* w2        = (const float*)d_in[3];
    const float* b2        = (const float*)d_in[4];
    const int*   hlist     = (const int*)d_in[6];
    const int*   wlist     = (const int*)d_in[7];
    float* out = (float*)d_out;
    s8v*   w2b = (s8v*)d_ws;   // 64 KB bf16 fragment table

    w2prep_kernel<<<16, 256, 0, stream>>>(w2, w2b);
    hgqg_kernel<<<NB * MAXH, 256, 0, stream>>>(
        canonical, w1, b1, w2b, b2, hlist, wlist, out);
}

// Round 4
// 280.506 us; speedup vs baseline: 1.1120x; 1.1120x over previous
//
#include <hip/hip_runtime.h>
#include <math.h>

// Problem constants: B=64, MAX_H=64, MAX_W=32, D=512, S=8, HID=64
#define NB    64
#define MAXH  64
#define MAXW  32
#define DCH   512
#define SS    8
#define HID   64

#define QTOTAL ((size_t)NB * MAXH * MAXW * DCH)   // 67,108,864 floats

typedef float f4  __attribute__((ext_vector_type(4)));
typedef short s8v __attribute__((ext_vector_type(8)));   // 8 bf16 (4 VGPRs)

__device__ __forceinline__ float gelu_exact(float x) {
    // jax.nn.gelu(approximate=False): x * 0.5 * (1 + erf(x/sqrt(2)))
    return 0.5f * x * (1.0f + erff(x * 0.70710678118654752440f));
}

__device__ __forceinline__ unsigned short bf16_rne(float x) {
    unsigned int u = __float_as_uint(x);
    unsigned int r = u + 0x7fffu + ((u >> 16) & 1u);
    return (unsigned short)(r >> 16);
}

// ---------------------------------------------------------------------------
// Prep: w2 (64x512 f32) -> bf16 table in MFMA fragment order (64 KB, d_ws).
// Lane l of a wave holds elems [k=(l>>4)*8+j][x=l&15], j=0..7 — this packing
// is IDENTICAL for the A-fragment (x=M-row) and B-fragment (x=N-col) of
// 16x16x32 bf16 MFMA. Table entry (kh, ct, lane):
//   k = 32*kh + (l>>4)*8 + j,  c = 16*ct + (l&15)
// Flat index = (kh*32 + ct)*64 + lane  (== tid below).
// ---------------------------------------------------------------------------
__global__ __launch_bounds__(256) void w2prep_kernel(
    const float* __restrict__ w2, s8v* __restrict__ w2b)
{
    const int tid  = blockIdx.x * 256 + threadIdx.x;   // 0..4095
    const int lane = tid & 63;
    const int ct   = (tid >> 6) & 31;
    const int kh   = tid >> 11;                        // 0..1
    const int q    = lane >> 4;
    const int m    = lane & 15;
    const int c    = ct * 16 + m;
    union { s8v v; unsigned short us[8]; } pk;
    #pragma unroll
    for (int j = 0; j < 8; ++j) {
        const int k = kh * 32 + q * 8 + j;
        pk.us[j] = bf16_rne(w2[k * DCH + c]);
    }
    w2b[tid] = pk.v;
}

// ---------------------------------------------------------------------------
// Main: one block = (b, i, half) -> 16 j x 512 c. 4 waves, each wave owns
// 128 channels = 8 MFMA tiles.
//
// TRANSPOSED MFMA: compute D = w2^T · h^T = delta^T by swapping the
// operands:  A = w2-chunk fragment (16c x K), B = h fragment (K x 16j).
// C/D layout: col = lane&15 = j_local, row = (lane>>4)*4 + r = c_local.
// => each lane owns ONE j and FOUR CONSECUTIVE channels: bilinear seed is
// ds_read_b128, output store is global_store_dwordx4.
//
// NOTE (R3 lesson): do NOT use nontemporal stores here — the wave's 64 B
// row-segments rely on L2 write-combining with the adjacent tile's segment
// to form full lines; nt bypass costs ~15-25 us via partial-line drain.
// ---------------------------------------------------------------------------
__global__ __launch_bounds__(256) void hgqg_kernel(
    const float* __restrict__ canonical,  // (8,8,512)
    const float* __restrict__ w1,         // (2,64)
    const float* __restrict__ b1,         // (64,)
    const s8v*   __restrict__ w2b,        // bf16 fragment table (d_ws)
    const float* __restrict__ b2,         // (512,)
    const int*   __restrict__ hlist,      // (64,)
    const int*   __restrict__ wlist,      // (64,)
    float* __restrict__ out)              // queries flat, then mask flat
{
    // bijective swizzle: spreads (b,i) across CUs
    const int raw  = blockIdx.x;                 // 0..8191
    const int id   = (raw ^ (raw >> 7)) & 8191;
    const int i    = id & 63;
    const int half = (id >> 6) & 1;
    const int b    = id >> 7;
    const int blk  = (b << 6) | i;
    const int t    = threadIdx.x;

    int H = hlist[b]; H = min(max(H, 1), MAXH);
    int W = wlist[b]; W = min(max(W, 1), MAXW);

    const int jbase = half << 4;                 // 0 or 16

    f4* q4 = (f4*)(out + (size_t)blk * (MAXW * DCH)) + jbase * 128;

    if (half == 0 && t < MAXW) {
        out[QTOTAL + (size_t)blk * MAXW + t] = (i < H && t < W) ? 1.0f : 0.0f;
    }

    const f4 z = {0.f, 0.f, 0.f, 0.f};

    if (i >= H || jbase >= W) {
        #pragma unroll
        for (int r = 0; r < 8; ++r) q4[t + r * 256] = z;
        return;
    }

    // ---- per-row uniforms ----
    const float u    = (H > 1) ? (float)i / (float)(H - 1) : 0.0f;
    const float sy   = fminf(u * 7.0f, 7.0f);
    const int   y0   = (int)sy;
    const int   y1   = min(y0 + 1, SS - 1);
    const float wy   = sy - (float)y0;
    const float winv = (W > 1) ? 1.0f / (float)(W - 1) : 0.0f;

    // ---- stage A: y-lerped canonical rows -> LDS, padded stride 516 ----
    __shared__ __align__(16) float ri[SS * 516];     // 16.5 KB
    {
        const f4* can4 = (const f4*)canonical;
        #pragma unroll
        for (int rr = 0; rr < 4; ++rr) {
            const int idx = t + rr * 256;     // 0..1023
            const int x   = idx >> 7;
            const int c4  = idx & 127;
            const f4 a = can4[(y0 * SS + x) * 128 + c4];
            const f4 d = can4[(y1 * SS + x) * 128 + c4];
            *(f4*)&ri[x * 516 + c4 * 4] = a + wy * (d - a);
        }
    }

    // ---- stage B: hsh[jl][k] = gelu(u*w1[0][k] + v*w1[1][k] + b1[k]) ----
    __shared__ __align__(16) float hsh[16][68];      // padded: bank spread
    {
        const int jl = t >> 4;              // 0..15
        const int k0 = (t & 15) * 4;        // 0..60
        const float v = (float)(jbase + jl) * winv;
        #pragma unroll
        for (int kk = 0; kk < 4; ++kk) {
            const int k = k0 + kk;
            hsh[jl][k] = gelu_exact(u * w1[k] + v * w1[HID + k] + b1[k]);
        }
    }
    __syncthreads();

    // ---- wave decomposition ----
    const int l = t & 63;          // lane
    const int w = t >> 6;          // wave 0..3 -> channels [w*128, w*128+128)
    const int q = l >> 4;          // quad
    const int m = l & 15;          // lane-in-quad

    // h-fragments (used as MFMA *B* operand): lane holds h[j=m][k=q*8+j]
    union { s8v v; unsigned short us[8]; } A0, A1;
    {
        const float* hrow = &hsh[m][q * 8];
        #pragma unroll
        for (int j = 0; j < 8; ++j) {
            A0.us[j] = bf16_rne(hrow[j]);
            A1.us[j] = bf16_rne(hrow[32 + j]);
        }
    }

    // per-lane x-weights: this lane's single output row j = jbase + m
    const int   jl  = jbase + m;
    const float vv  = (float)jl * winv;
    const float sx  = fminf(vv * 7.0f, 7.0f);
    const int   x0  = (int)sx;
    const int   x1  = min(x0 + 1, SS - 1);
    const float wx  = sx - (float)x0;
    const bool  jok = (jl < W);

    float* orow = out + (size_t)blk * (MAXW * DCH) + (size_t)jl * DCH;

    #pragma unroll
    for (int tt = 0; tt < 8; ++tt) {
        const int ct = w * 8 + tt;           // c-tile 0..31
        const int cb = ct * 16 + q * 4;      // 4 consecutive channels / lane

        // seed C with bilinear + b2 (row r = channel cb+r, col m = j)
        const f4 f0 = *(const f4*)&ri[x0 * 516 + cb];
        const f4 f1 = *(const f4*)&ri[x1 * 516 + cb];
        const f4 bb = *(const f4*)&b2[cb];
        f4 acc = f0 + wx * (f1 - f0) + bb;

        // delta^T: two chained K=32 MFMAs, A = w2 fragment, B = h fragment
        const s8v b0  = w2b[ct * 64 + l];            // kh=0
        const s8v b1f = w2b[2048 + ct * 64 + l];     // kh=1
        acc = __builtin_amdgcn_mfma_f32_16x16x32_bf16(b0,  A0.v, acc, 0, 0, 0);
        acc = __builtin_amdgcn_mfma_f32_16x16x32_bf16(b1f, A1.v, acc, 0, 0, 0);

        // store 16 B contiguous per lane; mask is lane-uniform (j >= W -> 0)
        const f4 res = jok ? acc : z;
        *(f4*)(orow + cb) = res;
    }
}

extern "C" void kernel_launch(void* const* d_in, const int* in_sizes, int n_in,
                              void* d_out, int out_size, void* d_ws, size_t ws_size,
                              hipStream_t stream) {
    const float* canonical = (const float*)d_in[0];
    const float* w1        = (const float*)d_in[1];
    const float* b1        = (const float*)d_in[2];
    const float* w2        = (const float*)d_in[3];
    const float* b2        = (const float*)d_in[4];
    const int*   hlist     = (const int*)d_in[6];
    const int*   wlist     = (const int*)d_in[7];
    float* out = (float*)d_out;
    s8v*   w2b = (s8v*)d_ws;   // 64 KB bf16 fragment table

    w2prep_kernel<<<16, 256, 0, stream>>>(w2, w2b);
    hgqg_kernel<<<2 * NB * MAXH, 256, 0, stream>>>(
        canonical, w1, b1, w2b, b2, hlist, wlist, out);
}